// Round 10
// baseline (239.204 us; speedup 1.0000x reference)
//
#include <hip/hip_runtime.h>
#include <hip/hip_bf16.h>

#define NUM_CLASSES 100000
#define DIM 256
#define BATCH 256
#define NUM_TRUE 1024
#define NUM_SAMPLED 16384
// ln(NUM_CLASSES + 1)
#define LOG_RANGE 11.51293546492023f
#define INV_LOG_RANGE (1.0f / LOG_RANGE)

#define SWEEP_BLOCKS 3126          // 3126 * 32 = 100032 classes (32 padded)

typedef __bf16 bf16x8 __attribute__((ext_vector_type(8)));
typedef float  f32x4  __attribute__((ext_vector_type(4)));

// RNE float -> bf16 bits
static __device__ __forceinline__ unsigned short f2bf(float f) {
    unsigned int u = __float_as_uint(f);
    unsigned int lsb = (u >> 16) & 1u;
    u += 0x7fffu + lsb;
    return (unsigned short)(u >> 16);
}

// -log(expected_count(id)), fast-math (validated r6-r9: absmax 0.0)
static __device__ __forceinline__ float neg_log_ec_fast(int id) {
    float idf = (float)id;
    float e = 1.0f / (idf + 1.0f);
    float p = log1pf(e) * INV_LOG_RANGE;
    float q = p * (1.0f + 0.5f * p + 0.3333333f * p * p);
    float ec = 1.0f - __expf(-(float)NUM_SAMPLED * q);
    return -__logf(ec);
}

// ---- scatter: 4-bit multiplicity table[c][b], sampled flags, inputs->bf16 ----
__global__ __launch_bounds__(256) void scatter_kernel(const int* __restrict__ labels,
                                                      const int* __restrict__ sampled,
                                                      const float* __restrict__ inputs,
                                                      unsigned int* __restrict__ table,
                                                      unsigned char* __restrict__ flags,
                                                      unsigned short* __restrict__ inbf) {
    const int gid = blockIdx.x * 256 + threadIdx.x;   // 262144 threads
    const int c = labels[gid];
    const int b = gid >> 10;                          // labels are [b][t] flat
    atomicAdd(&table[c * 32 + (b >> 3)], 1u << ((b & 7) * 4));
    if (gid < NUM_SAMPLED) {
        flags[sampled[gid]] = 1;                      // sampled ids unique
        float4 v = ((const float4*)inputs)[gid];      // 16384 float4s = all inputs
        ushort4 p;
        p.x = f2bf(v.x); p.y = f2bf(v.y); p.z = f2bf(v.z); p.w = f2bf(v.w);
        ((ushort4*)inbf)[gid] = p;
    }
}

// ---- sweep: full [100k x 256] logit GEMM; epilogue resolves true+sampled xent ----
// ONE WAVE PER BLOCK, 32 classes x 256 batch per wave. A-fragments straight from
// global w into 64 VGPRs (no LDS staging, no barriers); B from L2-hot inbf.
// 3126 independent waves ~ 3/SIMD resident: pure TLP latency hiding.
__global__ __launch_bounds__(64, 3) void sweep_kernel(const float* __restrict__ w,
                                                      const float* __restrict__ bias,
                                                      const unsigned int* __restrict__ table,
                                                      const unsigned char* __restrict__ flags,
                                                      const unsigned short* __restrict__ inbf,
                                                      float* __restrict__ partial) {
    __shared__ unsigned int lmask[32][33];   // +1 pad: epilogue reads conflict-free
    __shared__ float cs[32];                 // bias[c] - log(ec(c))
    __shared__ float sf[32];                 // 1.0 iff c in sampled set
    __shared__ float bacc[BATCH];

    const int lane = threadIdx.x;
    const int m    = lane & 15;
    const int quad = lane >> 4;
    const int c0   = blockIdx.x * 32;

    // masks: 1024 words coalesced (table zero-padded past NUM_CLASSES)
    {
        const unsigned int* src = table + (size_t)c0 * 32;
        #pragma unroll
        for (int i = 0; i < 16; ++i) {
            const int idx = i * 64 + lane;
            lmask[idx >> 5][idx & 31] = src[idx];
        }
    }
    if (lane < 32) {
        const int c = c0 + lane;
        const int cc = c < NUM_CLASSES ? c : NUM_CLASSES - 1;
        cs[lane] = bias[cc] + neg_log_ec_fast(c);
        sf[lane] = flags[c] ? 1.0f : 0.0f;    // pad classes: kf=0, sf=0 -> no-op
    }

    // A-fragments: 32 classes x full K, fp32 w -> bf16 regs (64 VGPRs)
    bf16x8 af[2][8];
    #pragma unroll
    for (int s = 0; s < 2; ++s) {
        int row = c0 + s * 16 + m;
        row = row < NUM_CLASSES ? row : NUM_CLASSES - 1;   // clamp: masked by kf=sf=0
        const float* wr = w + (size_t)row * DIM + quad * 8;
        #pragma unroll
        for (int kk = 0; kk < 8; ++kk) {
            float4 v0 = *(const float4*)(wr + kk * 32);
            float4 v1 = *(const float4*)(wr + kk * 32 + 4);
            union { unsigned short u[8]; bf16x8 b; } t;
            t.u[0] = f2bf(v0.x); t.u[1] = f2bf(v0.y); t.u[2] = f2bf(v0.z); t.u[3] = f2bf(v0.w);
            t.u[4] = f2bf(v1.x); t.u[5] = f2bf(v1.y); t.u[6] = f2bf(v1.z); t.u[7] = f2bf(v1.w);
            af[s][kk] = t.b;
        }
    }
    __syncthreads();   // single wave: just orders LDS writes vs reads (one barrier)

    #pragma unroll 1
    for (int tt = 0; tt < 16; ++tt) {
        const unsigned short* bp = inbf + (tt * 16 + m) * DIM + quad * 8;
        bf16x8 bf[8];
        #pragma unroll
        for (int kk = 0; kk < 8; ++kk) bf[kk] = *(const bf16x8*)(bp + kk * 32);
        f32x4 a0 = {0, 0, 0, 0}, a1 = {0, 0, 0, 0};
        #pragma unroll
        for (int kk = 0; kk < 8; ++kk) {
            a0 = __builtin_amdgcn_mfma_f32_16x16x32_bf16(af[0][kk], bf[kk], a0, 0, 0, 0);
            a1 = __builtin_amdgcn_mfma_f32_16x16x32_bf16(af[1][kk], bf[kk], a1, 0, 0, 0);
        }
        // epilogue: C/D row(class)=quad*4+r, col(batch)=m (r6-verified)
        const int widx = tt * 2 + (m >> 3);
        const int nsh  = (m & 7) * 4;
        float ps = 0.0f;
        #pragma unroll
        for (int r = 0; r < 4; ++r) {
            {
                const int cl = quad * 4 + r;
                float l = a0[r] + cs[cl];
                float kf = (float)((lmask[cl][widx] >> nsh) & 15u);
                float base = fmaxf(l, 0.0f) + __logf(1.0f + __expf(-fabsf(l)));
                ps += (kf + sf[cl]) * base - kf * l * (1.0f / (float)NUM_TRUE);
            }
            {
                const int cl = 16 + quad * 4 + r;
                float l = a1[r] + cs[cl];
                float kf = (float)((lmask[cl][widx] >> nsh) & 15u);
                float base = fmaxf(l, 0.0f) + __logf(1.0f + __expf(-fabsf(l)));
                ps += (kf + sf[cl]) * base - kf * l * (1.0f / (float)NUM_TRUE);
            }
        }
        ps += __shfl_xor(ps, 16); ps += __shfl_xor(ps, 32);   // sum the 4 quads
        if (quad == 0) bacc[tt * 16 + m] = ps;                // unique (tt,m): no atomic
    }
    __syncthreads();
    #pragma unroll
    for (int i = 0; i < 4; ++i)
        partial[(size_t)blockIdx.x * BATCH + i * 64 + lane] = bacc[i * 64 + lane];
}

// ---- final reduce: out[b] = sum over 3126 block partials ----
__global__ __launch_bounds__(256) void reduce_kernel(const float* __restrict__ partial,
                                                     float* __restrict__ out) {
    __shared__ float wsum[4];
    const int b = blockIdx.x;
    const int tid = threadIdx.x;
    float v = 0.0f;
    for (int j = tid; j < SWEEP_BLOCKS; j += 256)
        v += partial[(size_t)j * BATCH + b];
    v += __shfl_xor(v, 1);  v += __shfl_xor(v, 2);  v += __shfl_xor(v, 4);
    v += __shfl_xor(v, 8);  v += __shfl_xor(v, 16); v += __shfl_xor(v, 32);
    if ((tid & 63) == 0) wsum[tid >> 6] = v;
    __syncthreads();
    if (tid == 0) out[b] = wsum[0] + wsum[1] + wsum[2] + wsum[3];
}

extern "C" void kernel_launch(void* const* d_in, const int* in_sizes, int n_in,
                              void* d_out, int out_size, void* d_ws, size_t ws_size,
                              hipStream_t stream) {
    const float* inputs  = (const float*)d_in[0];   // [256,256]
    const float* w       = (const float*)d_in[1];   // [100000,256]
    const float* bias    = (const float*)d_in[2];   // [100000]
    const int*   labels  = (const int*)d_in[3];     // [256,1024]
    const int*   sampled = (const int*)d_in[4];     // [16384]
    float* out = (float*)d_out;                     // [256]

    // table padded to 100032 classes so the last sweep blocks read zeros
    unsigned int*   table   = (unsigned int*)d_ws;                        // 12,804,096 B
    unsigned char*  flags   = (unsigned char*)d_ws + 12804096;            // 100,032 B
    unsigned short* inbf    = (unsigned short*)((char*)d_ws + 12904128);  // 131,072 B
    float*          partial = (float*)((char*)d_ws + 13035200);           // 3,201,024 B

    hipMemsetAsync(d_ws, 0, 12904128, stream);      // table + flags
    scatter_kernel<<<(BATCH * NUM_TRUE) / 256, 256, 0, stream>>>(labels, sampled, inputs,
                                                                 table, flags, inbf);
    sweep_kernel<<<SWEEP_BLOCKS, 64, 0, stream>>>(w, bias, table, flags, inbf, partial);
    reduce_kernel<<<BATCH, 256, 0, stream>>>(partial, out);
}